// Round 3
// baseline (195.386 us; speedup 1.0000x reference)
//
#include <hip/hip_runtime.h>

#define BB 8192
#define TT 2048
#define NC 16    // time chunks
#define CL 128   // chunk length = TT/NC
#define WU 48    // h warmup steps (contraction ~0.5/step -> 1e-8 residual)

// z pre-scaled by -log2(e): sigmoid(z_orig) = rcp(1 + exp2(z))
__device__ __forceinline__ float sig2(float z) {
    return __builtin_amdgcn_rcpf(1.f + __builtin_amdgcn_exp2f(z));
}

// broadcast lane L (0..3) of each 4-lane quad via DPP quad_perm
template<int L>
__device__ __forceinline__ float qb(float v) {
    return __builtin_bit_cast(float,
        __builtin_amdgcn_mov_dpp(__builtin_bit_cast(int, v), L * 0x55, 0xF, 0xF, true));
}

// ---------------- sweep 1: h warmup + per-chunk affine latent maps ----------------
__global__ __launch_bounds__(256) void bkt_sweep1(
    const float* __restrict__ x, const float* __restrict__ Wxh,
    const float* __restrict__ Whh, const float* __restrict__ bh,
    const float* __restrict__ Wy, const float* __restrict__ by,
    float* __restrict__ AB, float* __restrict__ hstart)
{
    const int tid = blockIdx.x * 256 + threadIdx.x;
    const int q  = tid & 3;
    const int rc = tid >> 2;
    const int b  = rc & (BB - 1);
    const int c  = rc >> 13;              // BB = 2^13
    const float NL2E = -1.44269504088896340736f;

    float wyc[4], whc[4];
#pragma unroll
    for (int k = 0; k < 4; ++k) {
        wyc[k] = Wy[k * 4 + q]  * NL2E;
        whc[k] = Whh[k * 4 + q] * NL2E;
    }
    const float wxq = Wxh[q] * NL2E;
    const float bhq = bh[q]  * NL2E;
    const float byq = by[q]  * NL2E;

    const float* xr = x + (size_t)b * TT;
    float h = 0.f;
    const int tmain = c * CL;

    // --- warmup (h only); no iterations for c==0 (h=0 is exact there) ---
    for (int t0 = tmain - (c ? WU : 0); t0 < tmain; t0 += 16) {
        float xq4[4];
        *(float4*)xq4 = *(const float4*)(xr + t0 + 4 * q);
#define WSTEP(s)                                                                      \
        {                                                                             \
            float hb0 = qb<0>(h), hb1 = qb<1>(h), hb2 = qb<2>(h), hb3 = qb<3>(h);     \
            float xs = qb<(s) / 4>(xq4[(s) & 3]);                                     \
            float zh = fmaf(hb3, whc[3], fmaf(hb2, whc[2],                            \
                        fmaf(hb1, whc[1], fmaf(hb0, whc[0], fmaf(xs, wxq, bhq)))));   \
            h = sig2(zh);                                                             \
        }
        WSTEP(0)  WSTEP(1)  WSTEP(2)  WSTEP(3)
        WSTEP(4)  WSTEP(5)  WSTEP(6)  WSTEP(7)
        WSTEP(8)  WSTEP(9)  WSTEP(10) WSTEP(11)
        WSTEP(12) WSTEP(13) WSTEP(14) WSTEP(15)
#undef WSTEP
    }

    // --- main: compose affine latent map; evolve h ---
    float A = 1.f, Bc = 0.f;
    for (int t0 = tmain; t0 < tmain + CL; t0 += 16) {
        float xq4[4];
        *(float4*)xq4 = *(const float4*)(xr + t0 + 4 * q);
#define LSTEP(s)                                                                      \
        {                                                                             \
            float hb0 = qb<0>(h), hb1 = qb<1>(h), hb2 = qb<2>(h), hb3 = qb<3>(h);     \
            float zy = fmaf(hb3, wyc[3], fmaf(hb2, wyc[2],                            \
                        fmaf(hb1, wyc[1], fmaf(hb0, wyc[0], byq))));                  \
            float p  = sig2(zy);                                                      \
            float pl = qb<0>(p), pf = qb<1>(p);                                       \
            float a  = (1.f - pf) - pl;                                               \
            Bc = fmaf(a, Bc, pl);                                                     \
            A *= a;                                                                   \
            float xs = qb<(s) / 4>(xq4[(s) & 3]);                                     \
            float zh = fmaf(hb3, whc[3], fmaf(hb2, whc[2],                            \
                        fmaf(hb1, whc[1], fmaf(hb0, whc[0], fmaf(xs, wxq, bhq)))));   \
            h = sig2(zh);                                                             \
        }
        LSTEP(0)  LSTEP(1)  LSTEP(2)  LSTEP(3)
        LSTEP(4)  LSTEP(5)  LSTEP(6)  LSTEP(7)
        LSTEP(8)  LSTEP(9)  LSTEP(10) LSTEP(11)
        LSTEP(12) LSTEP(13) LSTEP(14) LSTEP(15)
#undef LSTEP
    }

    if (c < NC - 1) hstart[((size_t)(c + 1) * BB + b) * 4 + q] = h;
    if (q == 0) {
        AB[((size_t)c * BB + b) * 2 + 0] = A;
        AB[((size_t)c * BB + b) * 2 + 1] = Bc;
    }
}

// ---------------- middle pass: exact chunk-start latents ----------------
__global__ __launch_bounds__(256) void bkt_mid(
    const float* __restrict__ AB, const float* __restrict__ prior,
    float* __restrict__ latstart)
{
    const int b = blockIdx.x * 256 + threadIdx.x;   // 8192 threads
    float L = prior[0];
#pragma unroll
    for (int c = 0; c < NC; ++c) {
        latstart[(size_t)c * BB + b] = L;
        const float A  = AB[((size_t)c * BB + b) * 2 + 0];
        const float Bv = AB[((size_t)c * BB + b) * 2 + 1];
        L = fmaf(A, L, Bv);
    }
}

// ---------------- sweep 2: full outputs + loss ----------------
__global__ __launch_bounds__(256) void bkt_sweep2(
    const float* __restrict__ x, const float* __restrict__ y,
    const float* __restrict__ Wxh, const float* __restrict__ Whh,
    const float* __restrict__ bh, const float* __restrict__ Wy,
    const float* __restrict__ by,
    const float* __restrict__ hstart, const float* __restrict__ latstart,
    float* __restrict__ corrects, float* __restrict__ latents,
    float* __restrict__ partials)
{
    const int tid = blockIdx.x * 256 + threadIdx.x;
    const int q  = tid & 3;
    const int rc = tid >> 2;
    const int b  = rc & (BB - 1);
    const int c  = rc >> 13;
    const float NL2E = -1.44269504088896340736f;

    float wyc[4], whc[4];
#pragma unroll
    for (int k = 0; k < 4; ++k) {
        wyc[k] = Wy[k * 4 + q]  * NL2E;
        whc[k] = Whh[k * 4 + q] * NL2E;
    }
    const float wxq = Wxh[q] * NL2E;
    const float bhq = bh[q]  * NL2E;
    const float byq = by[q]  * NL2E;

    const float* xr = x + (size_t)b * TT;
    const float* yr = y + (size_t)b * TT;
    float* cr = corrects + (size_t)b * TT;
    float* lr = latents  + (size_t)b * TT;

    float h   = (c == 0) ? 0.f : hstart[((size_t)c * BB + b) * 4 + q];
    float lat = latstart[(size_t)c * BB + b];
    float lacc = 0.f;
    const int tmain = c * CL;

    for (int t0 = tmain; t0 < tmain + CL; t0 += 16) {
        float xq4[4], yq4[4], myc[4], myl[4];
        *(float4*)xq4 = *(const float4*)(xr + t0 + 4 * q);
        *(float4*)yq4 = *(const float4*)(yr + t0 + 4 * q);
#define STEP(s)                                                                       \
        {                                                                             \
            float hb0 = qb<0>(h), hb1 = qb<1>(h), hb2 = qb<2>(h), hb3 = qb<3>(h);     \
            float zy = fmaf(hb3, wyc[3], fmaf(hb2, wyc[2],                            \
                        fmaf(hb1, wyc[1], fmaf(hb0, wyc[0], byq))));                  \
            float p  = sig2(zy);                                                      \
            float pl = qb<0>(p), pf = qb<1>(p), pg = qb<2>(p), ps = qb<3>(p);         \
            float correct = fmaf(lat, (1.f - ps) - pg, pg);                           \
            float nlat    = fmaf(lat, (1.f - pf) - pl, pl);                           \
            float xs = qb<(s) / 4>(xq4[(s) & 3]);                                     \
            float ys = qb<(s) / 4>(yq4[(s) & 3]);                                     \
            float zh = fmaf(hb3, whc[3], fmaf(hb2, whc[2],                            \
                        fmaf(hb1, whc[1], fmaf(hb0, whc[0], fmaf(xs, wxq, bhq)))));   \
            float cc  = fminf(fmaxf(correct, 1e-7f), 1.f - 1e-7f);                    \
            float arg = fmaf(ys, fmaf(2.f, cc, -1.f), 1.f - cc);                      \
            lacc += __builtin_amdgcn_logf(arg);                                       \
            if (q == (s) / 4) { myc[(s) & 3] = correct; myl[(s) & 3] = nlat; }        \
            lat = nlat;                                                               \
            h = sig2(zh);                                                             \
        }
        STEP(0)  STEP(1)  STEP(2)  STEP(3)
        STEP(4)  STEP(5)  STEP(6)  STEP(7)
        STEP(8)  STEP(9)  STEP(10) STEP(11)
        STEP(12) STEP(13) STEP(14) STEP(15)
#undef STEP
        *(float4*)(cr + t0 + 4 * q) = *(float4*)myc;
        *(float4*)(lr + t0 + 4 * q) = *(float4*)myl;
    }

#pragma unroll
    for (int off = 32; off; off >>= 1) lacc += __shfl_down(lacc, off);
    if ((threadIdx.x & 63) == 0) partials[tid >> 6] = lacc;
}

__global__ __launch_bounds__(64) void bkt_loss(const float* __restrict__ partials, int n,
                                               float* __restrict__ out_loss)
{
    double s = 0.0;
    for (int i = threadIdx.x; i < n; i += 64) s += (double)partials[i];
#pragma unroll
    for (int off = 32; off; off >>= 1) s += __shfl_down(s, off);
    if (threadIdx.x == 0)
        *out_loss = (float)(-s * 0.69314718055994530942 / (4.0 * (double)BB * (double)TT));
}

extern "C" void kernel_launch(void* const* d_in, const int* in_sizes, int n_in,
                              void* d_out, int out_size, void* d_ws, size_t ws_size,
                              hipStream_t stream)
{
    const float* x     = (const float*)d_in[0];
    const float* y     = (const float*)d_in[1];
    const float* Wxh   = (const float*)d_in[2];
    const float* Whh   = (const float*)d_in[3];
    const float* bh    = (const float*)d_in[4];
    const float* Wy    = (const float*)d_in[5];
    const float* by    = (const float*)d_in[6];
    const float* prior = (const float*)d_in[7];

    float* out      = (float*)d_out;
    float* corrects = out;
    float* latents  = out + (size_t)BB * TT;
    float* lossp    = out + (size_t)2 * BB * TT;

    // workspace layout (floats)
    float* ws       = (float*)d_ws;
    float* AB       = ws;                                   // NC*BB*2
    float* hstart   = AB + (size_t)NC * BB * 2;             // NC*BB*4
    float* latstart = hstart + (size_t)NC * BB * 4;         // NC*BB
    float* partials = latstart + (size_t)NC * BB;           // 8192

    const int thr = BB * NC * 4;                            // 524288

    bkt_sweep1<<<thr / 256, 256, 0, stream>>>(x, Wxh, Whh, bh, Wy, by, AB, hstart);
    bkt_mid<<<BB / 256, 256, 0, stream>>>(AB, prior, latstart);
    bkt_sweep2<<<thr / 256, 256, 0, stream>>>(x, y, Wxh, Whh, bh, Wy, by,
                                              hstart, latstart,
                                              corrects, latents, partials);
    bkt_loss<<<1, 64, 0, stream>>>(partials, thr / 64, lossp);
}